// Round 1
// baseline (1207.132 us; speedup 1.0000x reference)
//
#include <hip/hip_runtime.h>
#include <hip/hip_bf16.h>
#include <math.h>

// Problem constants (from reference)
#define NN 20000      // nodes
#define NE 320000     // edges
#define FT 8          // tokens per node
#define DM 16         // embed dim
#define NH 4          // heads
#define DH 4          // head dim
#define FD 128        // FT*DM
#define OUTC 7        // classes
#define NFD (NN * FD)

// ---------------------------------------------------------------------------
// Per-node QKV projection: q/k/v[n,f,d] = sum_e x[n,f,e]*W[d,e] + b[d]
// One block (128 threads) per node; thread t -> (f = t>>4, d = t&15).
// Weights staged in LDS with stride-17 padding (16-row stride would be an
// 8-way bank conflict: d*16 mod 32 hits only 2 banks).
// ---------------------------------------------------------------------------
__global__ __launch_bounds__(128) void qkv_kernel(
    const float* __restrict__ x,
    const float* __restrict__ wqkv,   // [48][16]
    const float* __restrict__ bqkv,   // [48]
    float* __restrict__ q, float* __restrict__ k, float* __restrict__ v) {
    __shared__ float sx[FD];
    __shared__ float sw[48 * 17];
    __shared__ float sb[48];
    const int n = blockIdx.x;
    const int t = threadIdx.x;
    sx[t] = x[n * FD + t];
    for (int i = t; i < 48 * DM; i += 128) sw[(i >> 4) * 17 + (i & 15)] = wqkv[i];
    if (t < 48) sb[t] = bqkv[t];
    __syncthreads();
    const int f = t >> 4, d = t & 15;
    float aq = sb[d], ak = sb[DM + d], av = sb[2 * DM + d];
    const float* xr = &sx[f * DM];
#pragma unroll
    for (int e = 0; e < DM; ++e) {
        const float xe = xr[e];
        aq = fmaf(xe, sw[d * 17 + e], aq);
        ak = fmaf(xe, sw[(DM + d) * 17 + e], ak);
        av = fmaf(xe, sw[(2 * DM + d) * 17 + e], av);
    }
    q[n * FD + t] = aq;
    k[n * FD + t] = ak;
    v[n * FD + t] = av;
}

// ---------------------------------------------------------------------------
// Per-edge attention. 32 lanes per edge: lane -> (f = l>>2, h = l&3).
// q fragment for lane l is floats [4l, 4l+4) of dst row (coalesced float4).
// Softmax over g=8 is entirely lane-local. Output: 4 atomicAdds per lane
// into accum[dst] (Wo/bo hoisted past the segment-sum by linearity).
// ---------------------------------------------------------------------------
__global__ __launch_bounds__(256) void edge_attn_kernel(
    const int* __restrict__ src, const int* __restrict__ dst,
    const float* __restrict__ q, const float* __restrict__ k,
    const float* __restrict__ v, float* __restrict__ accum) {
    const int t = threadIdx.x;
    const int eid = blockIdx.x * 8 + (t >> 5);
    if (eid >= NE) return;
    const int hl = t & 31;
    const int h = hl & 3;
    const int s = src[eid];
    const int dn = dst[eid];

    const float4 qv = ((const float4*)(q + dn * FD))[hl];
    const float4* kp = (const float4*)(k + s * FD);
    const float4* vp = (const float4*)(v + s * FD);

    float4 kv[FT], vv[FT];
#pragma unroll
    for (int g = 0; g < FT; ++g) {
        kv[g] = kp[g * 4 + h];
        vv[g] = vp[g * 4 + h];
    }
    float sc[FT];
#pragma unroll
    for (int g = 0; g < FT; ++g)
        sc[g] = 0.5f * (qv.x * kv[g].x + qv.y * kv[g].y + qv.z * kv[g].z + qv.w * kv[g].w);

    float m = sc[0];
#pragma unroll
    for (int g = 1; g < FT; ++g) m = fmaxf(m, sc[g]);
    float sum = 0.f;
#pragma unroll
    for (int g = 0; g < FT; ++g) { sc[g] = __expf(sc[g] - m); sum += sc[g]; }
    const float inv = 1.0f / sum;

    float o0 = 0.f, o1 = 0.f, o2 = 0.f, o3 = 0.f;
#pragma unroll
    for (int g = 0; g < FT; ++g) {
        const float p = sc[g] * inv;
        o0 = fmaf(p, vv[g].x, o0);
        o1 = fmaf(p, vv[g].y, o1);
        o2 = fmaf(p, vv[g].z, o2);
        o3 = fmaf(p, vv[g].w, o3);
    }
    float* ap = accum + dn * FD + hl * 4;
    atomicAdd(ap + 0, o0);
    atomicAdd(ap + 1, o1);
    atomicAdd(ap + 2, o2);
    atomicAdd(ap + 3, o3);
}

// ---------------------------------------------------------------------------
// Per-node epilogue: h = ELU(accum @ Wo^T + deg * bo)
// ---------------------------------------------------------------------------
__global__ __launch_bounds__(128) void node_post_kernel(
    const float* __restrict__ accum, const int* __restrict__ deg,
    const float* __restrict__ wo,   // [16][16]
    const float* __restrict__ bo,   // [16]
    float* __restrict__ h) {
    __shared__ float sa[FD];
    __shared__ float sw[DM * 17];
    __shared__ float sb[DM];
    const int n = blockIdx.x;
    const int t = threadIdx.x;
    sa[t] = accum[n * FD + t];
    for (int i = t; i < DM * DM; i += 128) sw[(i >> 4) * 17 + (i & 15)] = wo[i];
    if (t < DM) sb[t] = bo[t];
    __syncthreads();
    const int f = t >> 4, d = t & 15;
    float acc = (float)deg[n] * sb[d];
#pragma unroll
    for (int e = 0; e < DM; ++e) acc = fmaf(sa[f * DM + e], sw[d * 17 + e], acc);
    h[n * FD + t] = acc > 0.f ? acc : expm1f(acc);
}

// ---------------------------------------------------------------------------
// deg[n] = in-degree at dst
// ---------------------------------------------------------------------------
__global__ __launch_bounds__(256) void deg_kernel(const int* __restrict__ dst,
                                                  int* __restrict__ deg) {
    const int e = blockIdx.x * 256 + threadIdx.x;
    if (e < NE) atomicAdd(&deg[dst[e]], 1);
}

// ---------------------------------------------------------------------------
// Classifier: logits = h @ W^T + b; log_softmax. One wave per node.
// ---------------------------------------------------------------------------
__global__ __launch_bounds__(256) void classifier_kernel(
    const float* __restrict__ h, const float* __restrict__ w,  // [7][128]
    const float* __restrict__ b, float* __restrict__ out) {
    const int lane = threadIdx.x & 63;
    const int n = blockIdx.x * 4 + (threadIdx.x >> 6);
    if (n >= NN) return;
    const float h0 = h[n * FD + lane];
    const float h1 = h[n * FD + 64 + lane];
    float acc[OUTC];
#pragma unroll
    for (int c = 0; c < OUTC; ++c)
        acc[c] = h0 * w[c * FD + lane] + h1 * w[c * FD + 64 + lane];
#pragma unroll
    for (int c = 0; c < OUTC; ++c) {
        float a = acc[c];
        for (int off = 32; off; off >>= 1) a += __shfl_xor(a, off);
        acc[c] = a;  // all lanes hold the full sum after butterfly
    }
    if (lane == 0) {
        float logits[OUTC];
        float m = -1e30f;
#pragma unroll
        for (int c = 0; c < OUTC; ++c) { logits[c] = acc[c] + b[c]; m = fmaxf(m, logits[c]); }
        float s = 0.f;
#pragma unroll
        for (int c = 0; c < OUTC; ++c) s += __expf(logits[c] - m);
        const float lse = m + logf(s);
#pragma unroll
        for (int c = 0; c < OUTC; ++c) out[n * OUTC + c] = logits[c] - lse;
    }
}

extern "C" void kernel_launch(void* const* d_in, const int* in_sizes, int n_in,
                              void* d_out, int out_size, void* d_ws, size_t ws_size,
                              hipStream_t stream) {
    const float* x      = (const float*)d_in[0];
    const int*   ei     = (const int*)d_in[1];
    const float* w1qkv  = (const float*)d_in[2];
    const float* b1qkv  = (const float*)d_in[3];
    const float* w1o    = (const float*)d_in[4];
    const float* b1o    = (const float*)d_in[5];
    const float* w2qkv  = (const float*)d_in[6];
    const float* b2qkv  = (const float*)d_in[7];
    const float* w2o    = (const float*)d_in[8];
    const float* b2o    = (const float*)d_in[9];
    const float* outw   = (const float*)d_in[10];
    const float* outb   = (const float*)d_in[11];
    float* out = (float*)d_out;

    const int* srcp = ei;        // edge_index[0]
    const int* dstp = ei + NE;   // edge_index[1]

    // Workspace: q,k,v,accum,hbuf (each N*128 f32 = 10.24 MB) + deg -> ~51.3 MB
    float* q     = (float*)d_ws;
    float* k     = q + NFD;
    float* v     = k + NFD;
    float* accum = v + NFD;
    float* hbuf  = accum + NFD;
    int*   deg   = (int*)(hbuf + NFD);

    hipMemsetAsync(deg, 0, NN * sizeof(int), stream);
    hipMemsetAsync(accum, 0, NFD * sizeof(float), stream);
    deg_kernel<<<(NE + 255) / 256, 256, 0, stream>>>(dstp, deg);

    // Layer 1
    qkv_kernel<<<NN, 128, 0, stream>>>(x, w1qkv, b1qkv, q, k, v);
    edge_attn_kernel<<<NE / 8, 256, 0, stream>>>(srcp, dstp, q, k, v, accum);
    node_post_kernel<<<NN, 128, 0, stream>>>(accum, deg, w1o, b1o, hbuf);

    // Layer 2
    hipMemsetAsync(accum, 0, NFD * sizeof(float), stream);
    qkv_kernel<<<NN, 128, 0, stream>>>(hbuf, w2qkv, b2qkv, q, k, v);
    edge_attn_kernel<<<NE / 8, 256, 0, stream>>>(srcp, dstp, q, k, v, accum);
    node_post_kernel<<<NN, 128, 0, stream>>>(accum, deg, w2o, b2o, hbuf);

    // Output head
    classifier_kernel<<<(NN + 3) / 4, 256, 0, stream>>>(hbuf, outw, outb, out);
}

// Round 2
// 305.366 us; speedup vs baseline: 3.9531x; 3.9531x over previous
//
#include <hip/hip_runtime.h>
#include <hip/hip_bf16.h>
#include <math.h>

// Problem constants (from reference)
#define NN 20000      // nodes
#define NE 320000     // edges
#define FT 8          // tokens per node
#define DM 16         // embed dim
#define NH 4          // heads
#define DH 4          // head dim
#define FD 128        // FT*DM
#define OUTC 7        // classes
#define NFD (NN * FD)

// ---------------------------------------------------------------------------
// Per-node QKV projection: q/k/v[n,f,d] = sum_e x[n,f,e]*W[d,e] + b[d]
// One block (128 threads) per node; thread t -> (f = t>>4, d = t&15).
// ---------------------------------------------------------------------------
__global__ __launch_bounds__(128) void qkv_kernel(
    const float* __restrict__ x,
    const float* __restrict__ wqkv,   // [48][16]
    const float* __restrict__ bqkv,   // [48]
    float* __restrict__ q, float* __restrict__ k, float* __restrict__ v) {
    __shared__ float sx[FD];
    __shared__ float sw[48 * 17];
    __shared__ float sb[48];
    const int n = blockIdx.x;
    const int t = threadIdx.x;
    sx[t] = x[n * FD + t];
    for (int i = t; i < 48 * DM; i += 128) sw[(i >> 4) * 17 + (i & 15)] = wqkv[i];
    if (t < 48) sb[t] = bqkv[t];
    __syncthreads();
    const int f = t >> 4, d = t & 15;
    float aq = sb[d], ak = sb[DM + d], av = sb[2 * DM + d];
    const float* xr = &sx[f * DM];
#pragma unroll
    for (int e = 0; e < DM; ++e) {
        const float xe = xr[e];
        aq = fmaf(xe, sw[d * 17 + e], aq);
        ak = fmaf(xe, sw[(DM + d) * 17 + e], ak);
        av = fmaf(xe, sw[(2 * DM + d) * 17 + e], av);
    }
    q[n * FD + t] = aq;
    k[n * FD + t] = ak;
    v[n * FD + t] = av;
}

// ---------------------------------------------------------------------------
// deg[n] = in-degree at dst (built once, reused by both layers + node_post)
// ---------------------------------------------------------------------------
__global__ __launch_bounds__(256) void deg_kernel(const int* __restrict__ dst,
                                                  int* __restrict__ deg) {
    const int e = blockIdx.x * 256 + threadIdx.x;
    if (e < NE) atomicAdd(&deg[dst[e]], 1);
}

// ---------------------------------------------------------------------------
// Single-block exclusive prefix scan of deg[0..NN) -> rowstart, cursor.
// 1024 threads, 20 chunks; wave-level shfl scan + LDS wave-sum scan.
// ---------------------------------------------------------------------------
__global__ __launch_bounds__(1024) void scan_kernel(const int* __restrict__ deg,
                                                    int* __restrict__ rowstart,
                                                    int* __restrict__ cursor) {
    __shared__ int wsum[16];
    __shared__ int s_carry;
    const int t = threadIdx.x;
    const int lane = t & 63, wid = t >> 6;
    if (t == 0) s_carry = 0;
    __syncthreads();
    for (int base = 0; base < NN; base += 1024) {
        const int i = base + t;
        const int d = (i < NN) ? deg[i] : 0;
        int s = d;
        for (int off = 1; off < 64; off <<= 1) {
            int tmp = __shfl_up(s, off);
            if (lane >= off) s += tmp;
        }
        if (lane == 63) wsum[wid] = s;
        __syncthreads();
        if (wid == 0) {
            int ws = (lane < 16) ? wsum[lane] : 0;
            for (int off = 1; off < 16; off <<= 1) {
                int tmp = __shfl_up(ws, off);
                if (lane >= off) ws += tmp;
            }
            if (lane < 16) wsum[lane] = ws;  // inclusive wave sums
        }
        __syncthreads();
        const int carry = s_carry;
        const int woff = (wid > 0) ? wsum[wid - 1] : 0;
        if (i < NN) {
            const int excl = carry + woff + s - d;
            rowstart[i] = excl;
            cursor[i] = excl;
        }
        __syncthreads();
        if (t == 1023) s_carry = carry + wsum[15];  // t1023 also owns wsum[15]
        __syncthreads();
    }
    if (t == 0) rowstart[NN] = NE;
}

// ---------------------------------------------------------------------------
// Scatter edges into CSR order (320k int atomics on 20k counters)
// ---------------------------------------------------------------------------
__global__ __launch_bounds__(256) void scatter_kernel(
    const int* __restrict__ src, const int* __restrict__ dst,
    int* __restrict__ cursor, int* __restrict__ csr_src) {
    const int e = blockIdx.x * 256 + threadIdx.x;
    if (e < NE) {
        const int pos = atomicAdd(&cursor[dst[e]], 1);
        csr_src[pos] = src[e];
    }
}

// ---------------------------------------------------------------------------
// Per-node edge aggregation (replaces per-edge kernel + float atomics).
// One 64-lane wave per dst node. Lane -> half (lane>>5) and (f,h) via
// hl = lane&31: f = hl>>2, h = hl&3. Halves process 2 edges per iteration;
// combined at the end with one shfl_xor(32). Q loaded once per node.
// Softmax over g=8 is lane-local. One coalesced float4 store per node.
// ---------------------------------------------------------------------------
__global__ __launch_bounds__(256) void edge_agg_kernel(
    const int* __restrict__ rowstart, const int* __restrict__ csr_src,
    const float* __restrict__ q, const float* __restrict__ k,
    const float* __restrict__ v, float* __restrict__ accum) {
    const int w = (blockIdx.x * 256 + threadIdx.x) >> 6;  // wave id = node
    if (w >= NN) return;
    const int lane = threadIdx.x & 63;
    const int hl = lane & 31;
    const int half = lane >> 5;
    const int h = hl & 3;

    const float4 qv = *(const float4*)(q + w * FD + hl * 4);
    const int beg = rowstart[w];
    const int end = rowstart[w + 1];

    float o0 = 0.f, o1 = 0.f, o2 = 0.f, o3 = 0.f;
    for (int e = beg + half; e < end; e += 2) {
        const int s = csr_src[e];
        const float4* kp = (const float4*)(k + s * FD);
        const float4* vp = (const float4*)(v + s * FD);
        float4 kv[FT], vv[FT];
#pragma unroll
        for (int g = 0; g < FT; ++g) {
            kv[g] = kp[g * 4 + h];
            vv[g] = vp[g * 4 + h];
        }
        float sc[FT];
#pragma unroll
        for (int g = 0; g < FT; ++g)
            sc[g] = 0.5f * (qv.x * kv[g].x + qv.y * kv[g].y + qv.z * kv[g].z + qv.w * kv[g].w);
        float m = sc[0];
#pragma unroll
        for (int g = 1; g < FT; ++g) m = fmaxf(m, sc[g]);
        float sum = 0.f;
#pragma unroll
        for (int g = 0; g < FT; ++g) { sc[g] = __expf(sc[g] - m); sum += sc[g]; }
        const float inv = 1.0f / sum;
#pragma unroll
        for (int g = 0; g < FT; ++g) {
            const float p = sc[g] * inv;
            o0 = fmaf(p, vv[g].x, o0);
            o1 = fmaf(p, vv[g].y, o1);
            o2 = fmaf(p, vv[g].z, o2);
            o3 = fmaf(p, vv[g].w, o3);
        }
    }
    o0 += __shfl_xor(o0, 32);
    o1 += __shfl_xor(o1, 32);
    o2 += __shfl_xor(o2, 32);
    o3 += __shfl_xor(o3, 32);
    if (half == 0)
        *(float4*)(accum + w * FD + hl * 4) = make_float4(o0, o1, o2, o3);
}

// ---------------------------------------------------------------------------
// Per-node epilogue: h = ELU(accum @ Wo^T + deg * bo)
// ---------------------------------------------------------------------------
__global__ __launch_bounds__(128) void node_post_kernel(
    const float* __restrict__ accum, const int* __restrict__ deg,
    const float* __restrict__ wo,   // [16][16]
    const float* __restrict__ bo,   // [16]
    float* __restrict__ h) {
    __shared__ float sa[FD];
    __shared__ float sw[DM * 17];
    __shared__ float sb[DM];
    const int n = blockIdx.x;
    const int t = threadIdx.x;
    sa[t] = accum[n * FD + t];
    for (int i = t; i < DM * DM; i += 128) sw[(i >> 4) * 17 + (i & 15)] = wo[i];
    if (t < DM) sb[t] = bo[t];
    __syncthreads();
    const int f = t >> 4, d = t & 15;
    float acc = (float)deg[n] * sb[d];
#pragma unroll
    for (int e = 0; e < DM; ++e) acc = fmaf(sa[f * DM + e], sw[d * 17 + e], acc);
    h[n * FD + t] = acc > 0.f ? acc : expm1f(acc);
}

// ---------------------------------------------------------------------------
// Classifier: logits = h @ W^T + b; log_softmax. One wave per node.
// ---------------------------------------------------------------------------
__global__ __launch_bounds__(256) void classifier_kernel(
    const float* __restrict__ h, const float* __restrict__ w,  // [7][128]
    const float* __restrict__ b, float* __restrict__ out) {
    const int lane = threadIdx.x & 63;
    const int n = blockIdx.x * 4 + (threadIdx.x >> 6);
    if (n >= NN) return;
    const float h0 = h[n * FD + lane];
    const float h1 = h[n * FD + 64 + lane];
    float acc[OUTC];
#pragma unroll
    for (int c = 0; c < OUTC; ++c)
        acc[c] = h0 * w[c * FD + lane] + h1 * w[c * FD + 64 + lane];
#pragma unroll
    for (int c = 0; c < OUTC; ++c) {
        float a = acc[c];
        for (int off = 32; off; off >>= 1) a += __shfl_xor(a, off);
        acc[c] = a;
    }
    if (lane == 0) {
        float logits[OUTC];
        float m = -1e30f;
#pragma unroll
        for (int c = 0; c < OUTC; ++c) { logits[c] = acc[c] + b[c]; m = fmaxf(m, logits[c]); }
        float s = 0.f;
#pragma unroll
        for (int c = 0; c < OUTC; ++c) s += __expf(logits[c] - m);
        const float lse = m + logf(s);
#pragma unroll
        for (int c = 0; c < OUTC; ++c) out[n * OUTC + c] = logits[c] - lse;
    }
}

extern "C" void kernel_launch(void* const* d_in, const int* in_sizes, int n_in,
                              void* d_out, int out_size, void* d_ws, size_t ws_size,
                              hipStream_t stream) {
    const float* x      = (const float*)d_in[0];
    const int*   ei     = (const int*)d_in[1];
    const float* w1qkv  = (const float*)d_in[2];
    const float* b1qkv  = (const float*)d_in[3];
    const float* w1o    = (const float*)d_in[4];
    const float* b1o    = (const float*)d_in[5];
    const float* w2qkv  = (const float*)d_in[6];
    const float* b2qkv  = (const float*)d_in[7];
    const float* w2o    = (const float*)d_in[8];
    const float* b2o    = (const float*)d_in[9];
    const float* outw   = (const float*)d_in[10];
    const float* outb   = (const float*)d_in[11];
    float* out = (float*)d_out;

    const int* srcp = ei;        // edge_index[0]
    const int* dstp = ei + NE;   // edge_index[1]

    // Workspace: q,k,v,accum (4 x N*128 f32 = 41 MB); hbuf aliases q (safe:
    // node_post runs after edge_agg; layer-2 qkv reads row n to LDS before
    // writing row n, blocks touch disjoint rows). + CSR ints ~1.5 MB.
    float* q     = (float*)d_ws;
    float* k     = q + NFD;
    float* v     = k + NFD;
    float* accum = v + NFD;
    float* hbuf  = q;  // alias
    int*   deg      = (int*)(accum + NFD);
    int*   rowstart = deg + NN;          // NN+1 entries
    int*   cursor   = rowstart + NN + 1;
    int*   csr_src  = cursor + NN;

    // Build CSR (once; shared by both layers)
    hipMemsetAsync(deg, 0, NN * sizeof(int), stream);
    deg_kernel<<<(NE + 255) / 256, 256, 0, stream>>>(dstp, deg);
    scan_kernel<<<1, 1024, 0, stream>>>(deg, rowstart, cursor);
    scatter_kernel<<<(NE + 255) / 256, 256, 0, stream>>>(srcp, dstp, cursor, csr_src);

    // Layer 1
    qkv_kernel<<<NN, 128, 0, stream>>>(x, w1qkv, b1qkv, q, k, v);
    edge_agg_kernel<<<NN / 4, 256, 0, stream>>>(rowstart, csr_src, q, k, v, accum);
    node_post_kernel<<<NN, 128, 0, stream>>>(accum, deg, w1o, b1o, hbuf);

    // Layer 2
    qkv_kernel<<<NN, 128, 0, stream>>>(hbuf, w2qkv, b2qkv, q, k, v);
    edge_agg_kernel<<<NN / 4, 256, 0, stream>>>(rowstart, csr_src, q, k, v, accum);
    node_post_kernel<<<NN, 128, 0, stream>>>(accum, deg, w2o, b2o, hbuf);

    // Output head
    classifier_kernel<<<(NN + 3) / 4, 256, 0, stream>>>(hbuf, outw, outb, out);
}